// Round 5
// baseline (3201.738 us; speedup 1.0000x reference)
//
#include <hip/hip_runtime.h>
#include <cstdint>

// ---------------- problem constants ----------------
#define NYD   256
#define NXD   256
#define PADC  22            // PML + FD_PAD
#define NYP_  300           // NY + 2*PAD
#define NXP_  300
#define GD    4             // guard ring width in the global halo arrays
#define ST    308           // global padded stride = NYP_ + 2*GD
#define NTT   250
#define NSHOT_ 2
#define NSRC_  8
#define NREC_  64
#define DT_   0.0005f

// strip decomposition
#define R_     5                     // rows per strip
#define NSTRIP 60                    // strips per shot (60*5 = 300)
#define NBLK   (NSHOT_ * NSTRIP)     // 120 blocks, all co-resident
#define NTHR   512
#define W_     304                   // LDS row width: 300 cols + 2 guard cols each side
#define WFR    (R_ + 8)              // 13 wf rows (radius-4 y-halo)
#define PYR    (R_ + 4)              // 9 psiy rows (radius-2 y-halo)

// barrier tree: 120 = 8 groups x 15
#define NGRP   8
#define GRPSZ  (NBLK / NGRP)         // 15

// ---------------- zero workspace ----------------
__global__ void zero_kernel(float* __restrict__ p, long n) {
    long i = (long)blockIdx.x * blockDim.x + threadIdx.x;
    long stride = (long)gridDim.x * blockDim.x;
    for (; i < n; i += stride) p[i] = 0.0f;
}

// ---------------- one-time setup: v2dt2, PML profiles, src/rec masks ----------------
__global__ void populate_kernel(const float* __restrict__ v,
                                const int* __restrict__ srcloc,
                                const int* __restrict__ recloc,
                                float* __restrict__ v2dt2,
                                float* __restrict__ prof,   // [2*ST]: a, b (guarded)
                                unsigned* __restrict__ srcmask,
                                unsigned long long* __restrict__ recmask) {
    const long f = (long)ST * ST;
    int i = blockIdx.x * 256 + threadIdx.x;

    if (i < NYP_ * NXP_) {
        int y = i / NXP_, x = i % NXP_;
        int vy = min(max(y - PADC, 0), NYD - 1);
        int vx = min(max(x - PADC, 0), NXD - 1);
        float vv = v[vy * NXD + vx];
        v2dt2[(y + GD) * ST + (x + GD)] = vv * vv * (DT_ * DT_);
    }

    if (i < NYP_) {  // DY == DX and NYP == NXP: one profile pair serves both axes
        float fi = (float)i;
        float d = fmaxf(22.0f - fi, fi - 277.0f);
        float frac = fminf(fmaxf(d * (1.0f / 20.0f), 0.0f), 1.0f);
        float sigma_max = 3.0f * 4000.0f * logf(1000.0f) / (2.0f * 20.0f * 5.0f);
        float sigma = sigma_max * frac * frac;
        float alpha = 3.14159265358979323846f * 25.0f * (1.0f - frac);
        float b = expf(-(sigma + alpha) * DT_);
        float a = sigma / (sigma + alpha + 1e-9f) * (b - 1.0f);
        prof[GD + i] = a;        // guard entries stay 0 from zero_kernel
        prof[ST + GD + i] = b;
    }

    if (i < NSHOT_ * NSRC_) {
        int sy = srcloc[2 * i] + PADC;
        int sx = srcloc[2 * i + 1] + PADC;
        int shot = i / NSRC_;
        int s = i % NSRC_;
        atomicOr(&srcmask[shot * f + (long)(sy + GD) * ST + (sx + GD)], 1u << s);
    }

    if (i >= 1024 && i < 1024 + NSHOT_ * NREC_) {
        int j = i - 1024;
        int ry = recloc[2 * j] + PADC;
        int rx = recloc[2 * j + 1] + PADC;
        int shot = j / NREC_;
        int r = j % NREC_;
        atomicOr(&recmask[shot * f + (long)(ry + GD) * ST + (rx + GD)], 1ull << r);
    }
}

// ---------------- software grid barrier, v2 ----------------
// R4 post-mortem: polling with atomicAdd(gen,0) is an RMW; 119 blocks spamming
// RMWs on one line serialize at the coherence point and the arrival RMWs queue
// behind them (~10us/step). v2: (1) waiters poll with a device-scope atomic
// LOAD (sc1, read-shared, no serialization); (2) arrivals go through an 8x15
// tree (group counters on separate cachelines, then root) so the RMW chain is
// 15+8 deep instead of 120.  bar layout (32-word spacing): [g*32] group
// counters g=0..7, [256] root, [288] gate.
__device__ __forceinline__ void grid_barrier(unsigned* bar, unsigned target) {
    __syncthreads();   // all waves' stores drained (compiler emits vmcnt(0))
    if (threadIdx.x == 0) {
        __threadfence();                               // release halo stores
        const unsigned g = blockIdx.x & (NGRP - 1);    // adjacent blocks spread
        bool opener = false;
        unsigned a = atomicAdd(&bar[g * 32], 1u) + 1u;
        if (a == (unsigned)GRPSZ * target) {
            unsigned r = atomicAdd(&bar[256], 1u) + 1u;
            if (r == (unsigned)NGRP * target) {
                __hip_atomic_store(&bar[288], target, __ATOMIC_RELEASE,
                                   __HIP_MEMORY_SCOPE_AGENT);
                opener = true;
            }
        }
        if (!opener) {
            while (__hip_atomic_load(&bar[288], __ATOMIC_RELAXED,
                                     __HIP_MEMORY_SCOPE_AGENT) < target)
                __builtin_amdgcn_s_sleep(2);
        }
        __threadfence();                               // acquire others' stores
    }
    __syncthreads();
}

// ---------------- persistent time loop, LDS-resident strips ----------------
// Each block owns a 5-row x 300-col strip of one shot. All state (wf x2, psiy,
// psix, zetay, zetax) lives in LDS; only halo rows (wf radius 4, psiy radius 2)
// cross blocks via ping-ponged global buffers. Per step: halo-in, phase A (psi
// update incl. recomputing psiy at the 2 halo rows each side), phase B
// (zeta/wf update + src/rec), halo-out, grid barrier.
__global__ __launch_bounds__(NTHR) void wave_persistent(
    float* __restrict__ gwf,      // [2 bufs][2 shots][ST*ST] halo exchange (wf)
    float* __restrict__ gpsiy,    // [2 bufs][2 shots][ST*ST] halo exchange (psiy)
    const float* __restrict__ v2dt2,
    const float* __restrict__ prof,
    const unsigned* __restrict__ srcmask,
    const unsigned long long* __restrict__ recmask,
    const float* __restrict__ amps,    // [NSHOT][NSRC][NT]
    float* __restrict__ out,           // [NSHOT][NREC][NT]
    unsigned* bar)
{
    __shared__ float lwf[2][WFR][W_];   // ping-pong wavefield (rows y0-4 .. y0+R+3)
    __shared__ float lpsiy[PYR][W_];    // rows y0-2 .. y0+R+1 (in-place update)
    __shared__ float lpsix[R_][W_];     // owned rows (in-place)
    __shared__ float lzy[R_][W_];
    __shared__ float lzx[R_][W_];
    __shared__ float la[ST], lb[ST];    // PML a/b profile (shared y/x axis)

    const int tid  = threadIdx.x;
    const int shot = blockIdx.x / NSTRIP;
    const int strip= blockIdx.x % NSTRIP;
    const int y0   = strip * R_;
    const long f   = (long)ST * ST;

    // ---- init LDS to zero, load profile ----
    for (int i = tid; i < 2 * WFR * W_; i += NTHR) ((float*)lwf)[i] = 0.0f;
    for (int i = tid; i < PYR * W_;     i += NTHR) ((float*)lpsiy)[i] = 0.0f;
    for (int i = tid; i < R_ * W_;      i += NTHR) {
        ((float*)lpsix)[i] = 0.0f; ((float*)lzy)[i] = 0.0f; ((float*)lzx)[i] = 0.0f;
    }
    for (int i = tid; i < ST; i += NTHR) { la[i] = prof[i]; lb[i] = prof[ST + i]; }

    // ---- per-owned-cell registers (3 cells/thread) ----
    float vdr[3]; unsigned smr[3]; unsigned long long rmr[3];
    int rr[3], col_[3]; bool act[3];
#pragma unroll
    for (int k = 0; k < 3; k++) {
        int i = tid + k * NTHR;
        act[k] = i < R_ * 300;
        int ii = act[k] ? i : 0;
        int r = ii / 300, c = ii % 300;
        rr[k] = r; col_[k] = c + 2;
        long gidx = (long)(GD + y0 + r) * ST + (GD + c);
        vdr[k] = v2dt2[gidx];
        smr[k] = srcmask[shot * f + gidx];
        rmr[k] = recmask[shot * f + gidx];
        if (!act[k]) { smr[k] = 0; rmr[k] = 0; }
    }
    __syncthreads();

    const float inv_h  = 0.2f;    // 1/DY
    const float inv_h2 = 0.04f;   // 1/DY^2
    const float C1A = 2.0f / 3.0f, C1B = 1.0f / 12.0f;
    const float C2A = 4.0f / 3.0f, C2B = -1.0f / 12.0f, C2C = -2.5f;

    for (int t = 0; t < NTT; t++) {
        const int p = t & 1;
        float (*wc)[W_] = lwf[p];        // wfc (state t)
        float (*wm)[W_] = lwf[1 - p];    // wfm (state t-1) -> becomes wfp
        const float* gwr = gwf   + ((long)(t & 1) * NSHOT_ + shot) * f;
        float*       gww = gwf   + ((long)((t + 1) & 1) * NSHOT_ + shot) * f;
        const float* gpr = gpsiy + ((long)(t & 1) * NSHOT_ + shot) * f;
        float*       gpw = gpsiy + ((long)((t + 1) & 1) * NSHOT_ + shot) * f;

        // ---- halo in: wf rows wl {0..3, 9..12}, psiy rows pl {0,1,7,8} ----
        for (int i = tid; i < 8 * W_; i += NTHR) {
            int hr = i / W_, col = i % W_;
            int wl = hr < 4 ? hr : hr + R_;
            int gy = y0 - 4 + wl;
            wc[wl][col] = gwr[(long)(GD + gy) * ST + 2 + col];
        }
        for (int i = tid; i < 4 * W_; i += NTHR) {
            int hr = i / W_, col = i % W_;
            int pl = hr < 2 ? hr : hr + R_;
            int gy = y0 - 2 + pl;
            lpsiy[pl][col] = gpr[(long)(GD + gy) * ST + 2 + col];
        }
        __syncthreads();

        // ---- phase A: psi updates (self-read -> in-place is race-free) ----
        for (int i = tid; i < PYR * 300; i += NTHR) {
            int pr = i / 300, c = i % 300, col = c + 2;
            int wl = pr + 2;
            float dwdy = (C1A * (wc[wl + 1][col] - wc[wl - 1][col])
                        - C1B * (wc[wl + 2][col] - wc[wl - 2][col])) * inv_h;
            int ya = GD + (y0 - 2 + pr);       // guard entries a=b=0 -> psiy=0 off-grid
            lpsiy[pr][col] = lb[ya] * lpsiy[pr][col] + la[ya] * dwdy;
        }
        for (int i = tid; i < R_ * 300; i += NTHR) {
            int r = i / 300, c = i % 300, col = c + 2;
            int wl = r + 4;
            float dwdx = (C1A * (wc[wl][col + 1] - wc[wl][col - 1])
                        - C1B * (wc[wl][col + 2] - wc[wl][col - 2])) * inv_h;
            int xa = col + 2;                  // GD + c
            lpsix[r][col] = lb[xa] * lpsix[r][col] + la[xa] * dwdx;
        }
        __syncthreads();

        // ---- phase B: zeta + wavefield update, src inject, halo out, record ----
#pragma unroll
        for (int k = 0; k < 3; k++) if (act[k]) {
            int r = rr[k], col = col_[k];
            int wl = r + 4, pl = r + 2;
            float w0 = wc[wl][col];
            float d2y = (C2B * (wc[wl - 2][col] + wc[wl + 2][col])
                       + C2A * (wc[wl - 1][col] + wc[wl + 1][col]) + C2C * w0) * inv_h2;
            float d2x = (C2B * (wc[wl][col - 2] + wc[wl][col + 2])
                       + C2A * (wc[wl][col - 1] + wc[wl][col + 1]) + C2C * w0) * inv_h2;
            float dpsiy = (C1A * (lpsiy[pl + 1][col] - lpsiy[pl - 1][col])
                         - C1B * (lpsiy[pl + 2][col] - lpsiy[pl - 2][col])) * inv_h;
            float dpsix = (C1A * (lpsix[r][col + 1] - lpsix[r][col - 1])
                         - C1B * (lpsix[r][col + 2] - lpsix[r][col - 2])) * inv_h;
            int ya = GD + y0 + r, xa = col + 2;
            float zy = lb[ya] * lzy[r][col] + la[ya] * (d2y + dpsiy);
            float zx = lb[xa] * lzx[r][col] + la[xa] * (d2x + dpsix);
            lzy[r][col] = zy; lzx[r][col] = zx;
            float lap = d2y + d2x + dpsiy + dpsix + zy + zx;
            float wfp = 2.0f * w0 - wm[wl][col] + vdr[k] * lap;

            unsigned sm = smr[k];
            if (sm) {
#pragma unroll
                for (int s = 0; s < NSRC_; s++)
                    if (sm & (1u << s)) wfp += vdr[k] * amps[(shot * NSRC_ + s) * NTT + t];
            }
            wm[wl][col] = wfp;   // in-place: wfm slot becomes wfp

            long gidx = (long)(GD + y0 + r) * ST + 2 + col;
            gww[gidx] = wfp;                                   // all 5 rows are edge rows
            if (r < 2 || r >= R_ - 2) gpw[gidx] = lpsiy[pl][col];  // rows {0,1,3,4}

            unsigned long long rm = rmr[k];
            while (rm) {
                int rec = __ffsll(rm) - 1;
                out[(shot * NREC_ + rec) * NTT + t] = wfp;
                rm &= rm - 1;
            }
        }

        grid_barrier(bar, (unsigned)(t + 1));
    }
}

// ---------------- host ----------------
extern "C" void kernel_launch(void* const* d_in, const int* in_sizes, int n_in,
                              void* d_out, int out_size, void* d_ws, size_t ws_size,
                              hipStream_t stream) {
    const float* v      = (const float*)d_in[0];
    const float* amps   = (const float*)d_in[1];
    const int*   srcloc = (const int*)d_in[2];
    const int*   recloc = (const int*)d_in[3];
    float* out = (float*)d_out;

    const long f = (long)ST * ST;
    float* base   = (float*)d_ws;
    float* gwf    = base;              // 2 bufs x 2 shots = 4f
    float* gpsiy  = gwf + 4 * f;       // 4f
    float* v2dt2  = gpsiy + 4 * f;     // f
    float* prof   = v2dt2 + f;         // 2*ST
    unsigned* srcmask = (unsigned*)(prof + 2 * ST);                        // 2f
    unsigned long long* recmask = (unsigned long long*)(srcmask + 2 * f);  // 4f words
    unsigned* bar = (unsigned*)(recmask + 2 * f);                          // 512 words

    const long total_words = 15 * f + 2 * ST + 512;

    zero_kernel<<<4096, 256, 0, stream>>>(base, total_words);
    populate_kernel<<<(NYP_ * NXP_ + 255) / 256, 256, 0, stream>>>(
        v, srcloc, recloc, v2dt2, prof, srcmask, recmask);

    wave_persistent<<<dim3(NBLK), dim3(NTHR), 0, stream>>>(
        gwf, gpsiy, v2dt2, prof, srcmask, recmask, amps, out, bar);
}

// Round 6
// 1618.078 us; speedup vs baseline: 1.9787x; 1.9787x over previous
//
#include <hip/hip_runtime.h>
#include <cstdint>

// ---------------- problem constants ----------------
#define NYD   256
#define NXD   256
#define PADC  22            // PML + FD_PAD
#define NYP_  300           // NY + 2*PAD
#define NXP_  300
#define GD    4             // guard ring width in the global halo arrays
#define ST    308           // global padded stride = NYP_ + 2*GD
#define NTT   250
#define NSHOT_ 2
#define NSRC_  8
#define NREC_  64
#define DT_   0.0005f

// strip decomposition
#define R_     5                     // rows per strip
#define NSTRIP 60                    // strips per shot (60*5 = 300)
#define NBLK   (NSHOT_ * NSTRIP)     // 120 blocks, all co-resident
#define NTHR   512
#define W_     304                   // LDS row width: 300 cols + 2 guard cols each side
#define WFR    (R_ + 8)              // 13 wf rows (radius-4 y-halo)
#define PYR    (R_ + 4)              // 9 psiy rows (radius-2 y-halo)

// barrier tree: 120 = 8 groups x 15
#define NGRP   8
#define GRPSZ  (NBLK / NGRP)         // 15

// agent-scope (device-coherent, sc1) access helpers — read/write the
// coherence point directly so NO cache fences (wbl2/inv) are ever needed.
__device__ __forceinline__ float ld_coherent(const float* p) {
    return __hip_atomic_load((const float*)p, __ATOMIC_RELAXED, __HIP_MEMORY_SCOPE_AGENT);
}
__device__ __forceinline__ void st_coherent(float* p, float v) {
    __hip_atomic_store(p, v, __ATOMIC_RELAXED, __HIP_MEMORY_SCOPE_AGENT);
}

// ---------------- zero workspace ----------------
__global__ void zero_kernel(float* __restrict__ p, long n) {
    long i = (long)blockIdx.x * blockDim.x + threadIdx.x;
    long stride = (long)gridDim.x * blockDim.x;
    for (; i < n; i += stride) p[i] = 0.0f;
}

// ---------------- one-time setup: v2dt2, PML profiles, src/rec masks ----------------
__global__ void populate_kernel(const float* __restrict__ v,
                                const int* __restrict__ srcloc,
                                const int* __restrict__ recloc,
                                float* __restrict__ v2dt2,
                                float* __restrict__ prof,   // [2*ST]: a, b (guarded)
                                unsigned* __restrict__ srcmask,
                                unsigned long long* __restrict__ recmask) {
    const long f = (long)ST * ST;
    int i = blockIdx.x * 256 + threadIdx.x;

    if (i < NYP_ * NXP_) {
        int y = i / NXP_, x = i % NXP_;
        int vy = min(max(y - PADC, 0), NYD - 1);
        int vx = min(max(x - PADC, 0), NXD - 1);
        float vv = v[vy * NXD + vx];
        v2dt2[(y + GD) * ST + (x + GD)] = vv * vv * (DT_ * DT_);
    }

    if (i < NYP_) {  // DY == DX and NYP == NXP: one profile pair serves both axes
        float fi = (float)i;
        float d = fmaxf(22.0f - fi, fi - 277.0f);
        float frac = fminf(fmaxf(d * (1.0f / 20.0f), 0.0f), 1.0f);
        float sigma_max = 3.0f * 4000.0f * logf(1000.0f) / (2.0f * 20.0f * 5.0f);
        float sigma = sigma_max * frac * frac;
        float alpha = 3.14159265358979323846f * 25.0f * (1.0f - frac);
        float b = expf(-(sigma + alpha) * DT_);
        float a = sigma / (sigma + alpha + 1e-9f) * (b - 1.0f);
        prof[GD + i] = a;        // guard entries stay 0 from zero_kernel
        prof[ST + GD + i] = b;
    }

    if (i < NSHOT_ * NSRC_) {
        int sy = srcloc[2 * i] + PADC;
        int sx = srcloc[2 * i + 1] + PADC;
        int shot = i / NSRC_;
        int s = i % NSRC_;
        atomicOr(&srcmask[shot * f + (long)(sy + GD) * ST + (sx + GD)], 1u << s);
    }

    if (i >= 1024 && i < 1024 + NSHOT_ * NREC_) {
        int j = i - 1024;
        int ry = recloc[2 * j] + PADC;
        int rx = recloc[2 * j + 1] + PADC;
        int shot = j / NREC_;
        int r = j % NREC_;
        atomicOr(&recmask[shot * f + (long)(ry + GD) * ST + (rx + GD)], 1ull << r);
    }
}

// ---------------- software grid barrier, v3: fence-free ----------------
// R5 post-mortem: the 12us/step floor was the __threadfence() pair — agent
// release/acquire lowers to buffer_wbl2 sc1 / buffer_inv sc1 (whole-L2
// invalidate), so every post-barrier read paid a coherence-point miss. v3:
// halo data itself moves with sc1 (agent-scope relaxed atomics), so the
// barrier needs NO cache maintenance: __syncthreads() drains each wave's
// outstanding sc1 stores (acked at the coherence point), arrival RMW + gate
// are agent-coherent, post-barrier sc1 loads must see pre-barrier sc1 stores.
__device__ __forceinline__ void grid_barrier(unsigned* bar, unsigned target) {
    __syncthreads();   // drains all waves' vmcnt -> halo stores at coherence point
    if (threadIdx.x == 0) {
        const unsigned g = blockIdx.x & (NGRP - 1);
        bool opener = false;
        unsigned a = __hip_atomic_fetch_add(&bar[g * 32], 1u,
                        __ATOMIC_RELAXED, __HIP_MEMORY_SCOPE_AGENT) + 1u;
        if (a == (unsigned)GRPSZ * target) {
            unsigned r = __hip_atomic_fetch_add(&bar[256], 1u,
                            __ATOMIC_RELAXED, __HIP_MEMORY_SCOPE_AGENT) + 1u;
            if (r == (unsigned)NGRP * target) {
                __hip_atomic_store(&bar[288], target,
                                   __ATOMIC_RELAXED, __HIP_MEMORY_SCOPE_AGENT);
                opener = true;
            }
        }
        if (!opener) {
            while (__hip_atomic_load(&bar[288], __ATOMIC_RELAXED,
                                     __HIP_MEMORY_SCOPE_AGENT) < target)
                __builtin_amdgcn_s_sleep(2);
        }
    }
    __syncthreads();
}

// ---------------- persistent time loop, LDS-resident strips ----------------
// Each block owns a 5-row x 300-col strip of one shot. All state (wf x2, psiy,
// psix, zetay, zetax) lives in LDS; only halo rows (wf radius 4, psiy radius 2)
// cross blocks via ping-ponged global buffers using sc1 accesses. Per step:
// halo-in, phase A (psi update incl. recomputing psiy at the 2 halo rows each
// side), phase B (zeta/wf update + src/rec + halo-out), fence-free barrier.
__global__ __launch_bounds__(NTHR) void wave_persistent(
    float* __restrict__ gwf,      // [2 bufs][2 shots][ST*ST] halo exchange (wf)
    float* __restrict__ gpsiy,    // [2 bufs][2 shots][ST*ST] halo exchange (psiy)
    const float* __restrict__ v2dt2,
    const float* __restrict__ prof,
    const unsigned* __restrict__ srcmask,
    const unsigned long long* __restrict__ recmask,
    const float* __restrict__ amps,    // [NSHOT][NSRC][NT]
    float* __restrict__ out,           // [NSHOT][NREC][NT]
    unsigned* bar)
{
    __shared__ float lwf[2][WFR][W_];   // ping-pong wavefield (rows y0-4 .. y0+R+3)
    __shared__ float lpsiy[PYR][W_];    // rows y0-2 .. y0+R+1 (in-place update)
    __shared__ float lpsix[R_][W_];     // owned rows (in-place)
    __shared__ float lzy[R_][W_];
    __shared__ float lzx[R_][W_];
    __shared__ float la[ST], lb[ST];    // PML a/b profile (shared y/x axis)

    const int tid  = threadIdx.x;
    const int shot = blockIdx.x / NSTRIP;
    const int strip= blockIdx.x % NSTRIP;
    const int y0   = strip * R_;
    const long f   = (long)ST * ST;

    // ---- init LDS to zero, load profile ----
    for (int i = tid; i < 2 * WFR * W_; i += NTHR) ((float*)lwf)[i] = 0.0f;
    for (int i = tid; i < PYR * W_;     i += NTHR) ((float*)lpsiy)[i] = 0.0f;
    for (int i = tid; i < R_ * W_;      i += NTHR) {
        ((float*)lpsix)[i] = 0.0f; ((float*)lzy)[i] = 0.0f; ((float*)lzx)[i] = 0.0f;
    }
    for (int i = tid; i < ST; i += NTHR) { la[i] = prof[i]; lb[i] = prof[ST + i]; }

    // ---- per-owned-cell registers (3 cells/thread) ----
    float vdr[3]; unsigned smr[3]; unsigned long long rmr[3];
    int rr[3], col_[3]; bool act[3];
#pragma unroll
    for (int k = 0; k < 3; k++) {
        int i = tid + k * NTHR;
        act[k] = i < R_ * 300;
        int ii = act[k] ? i : 0;
        int r = ii / 300, c = ii % 300;
        rr[k] = r; col_[k] = c + 2;
        long gidx = (long)(GD + y0 + r) * ST + (GD + c);
        vdr[k] = v2dt2[gidx];
        smr[k] = srcmask[shot * f + gidx];
        rmr[k] = recmask[shot * f + gidx];
        if (!act[k]) { smr[k] = 0; rmr[k] = 0; }
    }
    __syncthreads();

    const float inv_h  = 0.2f;    // 1/DY
    const float inv_h2 = 0.04f;   // 1/DY^2
    const float C1A = 2.0f / 3.0f, C1B = 1.0f / 12.0f;
    const float C2A = 4.0f / 3.0f, C2B = -1.0f / 12.0f, C2C = -2.5f;

    for (int t = 0; t < NTT; t++) {
        const int p = t & 1;
        float (*wc)[W_] = lwf[p];        // wfc (state t)
        float (*wm)[W_] = lwf[1 - p];    // wfm (state t-1) -> becomes wfp
        const float* gwr = gwf   + ((long)(t & 1) * NSHOT_ + shot) * f;
        float*       gww = gwf   + ((long)((t + 1) & 1) * NSHOT_ + shot) * f;
        const float* gpr = gpsiy + ((long)(t & 1) * NSHOT_ + shot) * f;
        float*       gpw = gpsiy + ((long)((t + 1) & 1) * NSHOT_ + shot) * f;

        // ---- halo in (sc1): wf rows wl {0..3, 9..12}, psiy rows pl {0,1,7,8} ----
        for (int i = tid; i < 8 * W_; i += NTHR) {
            int hr = i / W_, col = i % W_;
            int wl = hr < 4 ? hr : hr + R_;
            int gy = y0 - 4 + wl;
            wc[wl][col] = ld_coherent(&gwr[(long)(GD + gy) * ST + 2 + col]);
        }
        for (int i = tid; i < 4 * W_; i += NTHR) {
            int hr = i / W_, col = i % W_;
            int pl = hr < 2 ? hr : hr + R_;
            int gy = y0 - 2 + pl;
            lpsiy[pl][col] = ld_coherent(&gpr[(long)(GD + gy) * ST + 2 + col]);
        }
        __syncthreads();

        // ---- phase A: psi updates (self-read -> in-place is race-free) ----
        for (int i = tid; i < PYR * 300; i += NTHR) {
            int pr = i / 300, c = i % 300, col = c + 2;
            int wl = pr + 2;
            float dwdy = (C1A * (wc[wl + 1][col] - wc[wl - 1][col])
                        - C1B * (wc[wl + 2][col] - wc[wl - 2][col])) * inv_h;
            int ya = GD + (y0 - 2 + pr);       // guard entries a=b=0 -> psiy=0 off-grid
            lpsiy[pr][col] = lb[ya] * lpsiy[pr][col] + la[ya] * dwdy;
        }
        for (int i = tid; i < R_ * 300; i += NTHR) {
            int r = i / 300, c = i % 300, col = c + 2;
            int wl = r + 4;
            float dwdx = (C1A * (wc[wl][col + 1] - wc[wl][col - 1])
                        - C1B * (wc[wl][col + 2] - wc[wl][col - 2])) * inv_h;
            int xa = col + 2;                  // GD + c
            lpsix[r][col] = lb[xa] * lpsix[r][col] + la[xa] * dwdx;
        }
        __syncthreads();

        // ---- phase B: zeta + wavefield update, src inject, halo out, record ----
#pragma unroll
        for (int k = 0; k < 3; k++) if (act[k]) {
            int r = rr[k], col = col_[k];
            int wl = r + 4, pl = r + 2;
            float w0 = wc[wl][col];
            float d2y = (C2B * (wc[wl - 2][col] + wc[wl + 2][col])
                       + C2A * (wc[wl - 1][col] + wc[wl + 1][col]) + C2C * w0) * inv_h2;
            float d2x = (C2B * (wc[wl][col - 2] + wc[wl][col + 2])
                       + C2A * (wc[wl][col - 1] + wc[wl][col + 1]) + C2C * w0) * inv_h2;
            float dpsiy = (C1A * (lpsiy[pl + 1][col] - lpsiy[pl - 1][col])
                         - C1B * (lpsiy[pl + 2][col] - lpsiy[pl - 2][col])) * inv_h;
            float dpsix = (C1A * (lpsix[r][col + 1] - lpsix[r][col - 1])
                         - C1B * (lpsix[r][col + 2] - lpsix[r][col - 2])) * inv_h;
            int ya = GD + y0 + r, xa = col + 2;
            float zy = lb[ya] * lzy[r][col] + la[ya] * (d2y + dpsiy);
            float zx = lb[xa] * lzx[r][col] + la[xa] * (d2x + dpsix);
            lzy[r][col] = zy; lzx[r][col] = zx;
            float lap = d2y + d2x + dpsiy + dpsix + zy + zx;
            float wfp = 2.0f * w0 - wm[wl][col] + vdr[k] * lap;

            unsigned sm = smr[k];
            if (sm) {
#pragma unroll
                for (int s = 0; s < NSRC_; s++)
                    if (sm & (1u << s)) wfp += vdr[k] * amps[(shot * NSRC_ + s) * NTT + t];
            }
            wm[wl][col] = wfp;   // in-place: wfm slot becomes wfp

            long gidx = (long)(GD + y0 + r) * ST + 2 + col;
            st_coherent(&gww[gidx], wfp);                      // all 5 rows are edge rows
            if (r < 2 || r >= R_ - 2)
                st_coherent(&gpw[gidx], lpsiy[pl][col]);       // rows {0,1,3,4}

            unsigned long long rm = rmr[k];
            while (rm) {
                int rec = __ffsll(rm) - 1;
                out[(shot * NREC_ + rec) * NTT + t] = wfp;
                rm &= rm - 1;
            }
        }

        grid_barrier(bar, (unsigned)(t + 1));
    }
}

// ---------------- host ----------------
extern "C" void kernel_launch(void* const* d_in, const int* in_sizes, int n_in,
                              void* d_out, int out_size, void* d_ws, size_t ws_size,
                              hipStream_t stream) {
    const float* v      = (const float*)d_in[0];
    const float* amps   = (const float*)d_in[1];
    const int*   srcloc = (const int*)d_in[2];
    const int*   recloc = (const int*)d_in[3];
    float* out = (float*)d_out;

    const long f = (long)ST * ST;
    float* base   = (float*)d_ws;
    float* gwf    = base;              // 2 bufs x 2 shots = 4f
    float* gpsiy  = gwf + 4 * f;       // 4f
    float* v2dt2  = gpsiy + 4 * f;     // f
    float* prof   = v2dt2 + f;         // 2*ST
    unsigned* srcmask = (unsigned*)(prof + 2 * ST);                        // 2f
    unsigned long long* recmask = (unsigned long long*)(srcmask + 2 * f);  // 4f words
    unsigned* bar = (unsigned*)(recmask + 2 * f);                          // 512 words

    const long total_words = 15 * f + 2 * ST + 512;

    zero_kernel<<<4096, 256, 0, stream>>>(base, total_words);
    populate_kernel<<<(NYP_ * NXP_ + 255) / 256, 256, 0, stream>>>(
        v, srcloc, recloc, v2dt2, prof, srcmask, recmask);

    wave_persistent<<<dim3(NBLK), dim3(NTHR), 0, stream>>>(
        gwf, gpsiy, v2dt2, prof, srcmask, recmask, amps, out, bar);
}